// Round 1
// baseline (153.915 us; speedup 1.0000x reference)
//
#include <hip/hip_runtime.h>

#define WINDOW 9
#define RADIUS 4
#define MAX_DISP 192

// Problem dims fixed by setup_inputs()
constexpr int B  = 2;
constexpr int H  = 256;
constexpr int W  = 512;
constexpr int Hc = H - 2 * RADIUS;  // 248
constexpr int Wc = W - 2 * RADIUS;  // 504
constexpr int TOTAL = B * Hc * Wc; // 249984

// Compute 80-bit census signature at full-image center (cy, cx).
// Bit order: row-major over the 9x9 window skipping the center —
// order only needs to be consistent between left and right (Hamming dist).
__device__ __forceinline__ void census80(const float* __restrict__ base,
                                         int cy, int cx,
                                         unsigned long long& lo,
                                         unsigned long long& hi) {
    const float c = base[cy * W + cx];
    unsigned long long l = 0, h = 0;
    int bit = 0;
    #pragma unroll
    for (int i = -RADIUS; i <= RADIUS; ++i) {
        #pragma unroll
        for (int j = -RADIUS; j <= RADIUS; ++j) {
            if (i == 0 && j == 0) continue;
            const float v = base[(cy + i) * W + (cx + j)];
            const unsigned long long t = (v > c) ? 1ull : 0ull;
            if (bit < 64) l |= t << bit;
            else          h |= t << (bit - 64);
            ++bit;
        }
    }
    lo = l; hi = h;
}

__global__ void census_loss_kernel(const float* __restrict__ left,
                                   const float* __restrict__ right,
                                   const float* __restrict__ disp,
                                   unsigned int* __restrict__ acc) {
    const int idx = blockIdx.x * blockDim.x + threadIdx.x;

    unsigned int my_cost = 0;
    unsigned int my_cnt  = 0;

    if (idx < TOTAL) {
        const int x = idx % Wc;
        const int y = (idx / Wc) % Hc;
        const int b = idx / (Wc * Hc);

        const float dval = disp[((size_t)b * H + (y + RADIUS)) * W + (x + RADIUS)];
        if (dval > 0.0f) {
            my_cnt = 1;
            int d = (int)dval;
            d = max(0, min(MAX_DISP - 1, d));

            const float* lbase = left  + (size_t)b * H * W;
            const float* rbase = right + (size_t)b * H * W;

            unsigned long long llo, lhi;
            census80(lbase, y + RADIUS, x + RADIUS, llo, lhi);

            if (x + d < Wc) {
                unsigned long long rlo, rhi;
                census80(rbase, y + RADIUS, x + d + RADIUS, rlo, rhi);
                my_cost = (unsigned int)(__popcll(llo ^ rlo) + __popcll(lhi ^ rhi));
            } else {
                // invalid disparity column: rc_d == 0 vector -> cost = popcount(left)
                my_cost = (unsigned int)(__popcll(llo) + __popcll(lhi));
            }
        }
    }

    // wave-64 shuffle reduction, one atomic pair per wave
    #pragma unroll
    for (int off = 32; off > 0; off >>= 1) {
        my_cost += __shfl_down(my_cost, off);
        my_cnt  += __shfl_down(my_cnt,  off);
    }
    if ((threadIdx.x & 63) == 0) {
        atomicAdd(&acc[0], my_cost);
        atomicAdd(&acc[1], my_cnt);
    }
}

__global__ void finalize_kernel(const unsigned int* __restrict__ acc,
                                float* __restrict__ out) {
    out[0] = (float)acc[0] / ((float)acc[1] + 1e-6f);
}

extern "C" void kernel_launch(void* const* d_in, const int* in_sizes, int n_in,
                              void* d_out, int out_size, void* d_ws, size_t ws_size,
                              hipStream_t stream) {
    const float* left  = (const float*)d_in[0];
    const float* right = (const float*)d_in[1];
    const float* disp  = (const float*)d_in[2];
    float* out = (float*)d_out;
    unsigned int* acc = (unsigned int*)d_ws;   // [0] = cost sum, [1] = valid count

    // d_ws is poisoned 0xAA before every call — zero the accumulators.
    hipMemsetAsync(acc, 0, 2 * sizeof(unsigned int), stream);

    const int block = 256;
    const int grid  = (TOTAL + block - 1) / block;
    census_loss_kernel<<<grid, block, 0, stream>>>(left, right, disp, acc);
    finalize_kernel<<<1, 1, 0, stream>>>(acc, out);
}